// Round 1
// baseline (3233.110 us; speedup 1.0000x reference)
//
#include <hip/hip_runtime.h>

#define N_NODES 100000
#define E_EDGES 1600000
#define DIM 128
#define HID 64
#define NGRAPH 8
#define EPSBN 1e-5f

// ---------------------------------------------------------------------------
// mm1: y1 = x @ W1l, y2 = x @ W1r   (thread per row; W loads are uniform ->
// scalarized by compiler; 64 f32 accumulators in VGPRs)
// ---------------------------------------------------------------------------
__global__ __launch_bounds__(256) void mm1_kernel(
    const float* __restrict__ x, const float* __restrict__ W1l,
    const float* __restrict__ W1r, float* __restrict__ y1,
    float* __restrict__ y2) {
  int n = blockIdx.x * blockDim.x + threadIdx.x;
  if (n >= N_NODES) return;
  const float* xr = x + (size_t)n * DIM;

  float acc[HID];
  // pass 1: W1l -> y1
  #pragma unroll
  for (int j = 0; j < HID; ++j) acc[j] = 0.f;
  for (int k = 0; k < DIM; k += 4) {
    float4 xv = *reinterpret_cast<const float4*>(xr + k);
    float xs[4] = {xv.x, xv.y, xv.z, xv.w};
    #pragma unroll
    for (int kk = 0; kk < 4; ++kk) {
      const float* wrow = W1l + (size_t)(k + kk) * HID;
      float xk = xs[kk];
      #pragma unroll
      for (int j = 0; j < HID; ++j) acc[j] = fmaf(xk, wrow[j], acc[j]);
    }
  }
  {
    float4* o = reinterpret_cast<float4*>(y1 + (size_t)n * HID);
    #pragma unroll
    for (int q = 0; q < HID / 4; ++q)
      o[q] = make_float4(acc[4*q], acc[4*q+1], acc[4*q+2], acc[4*q+3]);
  }
  // pass 2: W1r -> y2
  #pragma unroll
  for (int j = 0; j < HID; ++j) acc[j] = 0.f;
  for (int k = 0; k < DIM; k += 4) {
    float4 xv = *reinterpret_cast<const float4*>(xr + k);
    float xs[4] = {xv.x, xv.y, xv.z, xv.w};
    #pragma unroll
    for (int kk = 0; kk < 4; ++kk) {
      const float* wrow = W1r + (size_t)(k + kk) * HID;
      float xk = xs[kk];
      #pragma unroll
      for (int j = 0; j < HID; ++j) acc[j] = fmaf(xk, wrow[j], acc[j]);
    }
  }
  {
    float4* o = reinterpret_cast<float4*>(y2 + (size_t)n * HID);
    #pragma unroll
    for (int q = 0; q < HID / 4; ++q)
      o[q] = make_float4(acc[4*q], acc[4*q+1], acc[4*q+2], acc[4*q+3]);
  }
}

// ---------------------------------------------------------------------------
// agg: scatter-add y[src] rows into accum[dst]; 16 threads per edge (float4
// per thread).  DO_CNT: also histogram edge counts per dst.
// ---------------------------------------------------------------------------
template <bool DO_CNT>
__global__ __launch_bounds__(256) void agg_kernel(
    const float* __restrict__ y, const int* __restrict__ src,
    const int* __restrict__ dst, float* __restrict__ accum,
    float* __restrict__ cnt) {
  unsigned t = blockIdx.x * blockDim.x + threadIdx.x;
  if (t >= (unsigned)E_EDGES * 16u) return;
  int e  = (int)(t >> 4);
  int c4 = ((int)t & 15) * 4;
  int s = src[e];
  int d = dst[e];
  float4 v = *reinterpret_cast<const float4*>(y + (size_t)s * HID + c4);
  float* ap = accum + (size_t)d * HID + c4;
  unsafeAtomicAdd(ap + 0, v.x);
  unsafeAtomicAdd(ap + 1, v.y);
  unsafeAtomicAdd(ap + 2, v.z);
  unsafeAtomicAdd(ap + 3, v.w);
  if (DO_CNT && c4 == 0) unsafeAtomicAdd(cnt + d, 1.0f);
}

// ---------------------------------------------------------------------------
// hcalc: h_raw = C/max(cnt,1) + b1 + y2, written in place into C.
// Fused BN statistics (per-column sum, sumsq) -> stats[0..63]=sum,
// stats[64..127]=sumsq.  Launch: grid*block multiple of 64.
// ---------------------------------------------------------------------------
__global__ __launch_bounds__(256) void hcalc_kernel(
    float* __restrict__ C, const float* __restrict__ y2,
    const float* __restrict__ cnt, const float* __restrict__ b1,
    float* __restrict__ stats) {
  __shared__ float ssum[HID];
  __shared__ float ssq[HID];
  int tid = threadIdx.x;
  if (tid < HID) { ssum[tid] = 0.f; ssq[tid] = 0.f; }
  __syncthreads();

  int j = tid & 63;
  float bj = b1[j];
  float lsum = 0.f, lsq = 0.f;
  long long stride = (long long)gridDim.x * blockDim.x;  // multiple of 64
  for (long long idx = (long long)blockIdx.x * blockDim.x + tid;
       idx < (long long)N_NODES * HID; idx += stride) {
    int n = (int)(idx >> 6);
    float c = cnt[n];
    c = c > 1.f ? c : 1.f;
    float val = C[idx] / c + bj + y2[idx];
    C[idx] = val;
    lsum += val;
    lsq  = fmaf(val, val, lsq);
  }
  atomicAdd(&ssum[j], lsum);
  atomicAdd(&ssq[j], lsq);
  __syncthreads();
  if (tid < HID) {
    unsafeAtomicAdd(&stats[tid], ssum[tid]);
    unsafeAtomicAdd(&stats[HID + tid], ssq[tid]);
  }
}

// ---------------------------------------------------------------------------
// bnstats: scale = gamma*rsqrt(var+eps), shift = beta - mu*scale
// ---------------------------------------------------------------------------
__global__ void bnstats_kernel(const float* __restrict__ stats,
                               const float* __restrict__ gamma,
                               const float* __restrict__ beta,
                               float* __restrict__ scsh) {
  int j = threadIdx.x;  // 64 threads
  float inv_n = 1.0f / (float)N_NODES;
  float mu = stats[j] * inv_n;
  float var = stats[HID + j] * inv_n - mu * mu;
  float sc = gamma[j] * rsqrtf(var + EPSBN);
  scsh[j] = sc;
  scsh[HID + j] = beta[j] - mu * sc;
}

// ---------------------------------------------------------------------------
// mm2: h = relu(h_raw*scale+shift); z1 = h@W2l; z2 = h@W2r (thread per row)
// ---------------------------------------------------------------------------
__global__ __launch_bounds__(256) void mm2_kernel(
    const float* __restrict__ C, const float* __restrict__ scsh,
    const float* __restrict__ W2l, const float* __restrict__ W2r,
    float* __restrict__ z1, float* __restrict__ z2) {
  int n = blockIdx.x * blockDim.x + threadIdx.x;
  if (n >= N_NODES) return;
  const float* hr = C + (size_t)n * HID;

  float h[HID];
  #pragma unroll
  for (int q = 0; q < HID / 4; ++q) {
    float4 v = *reinterpret_cast<const float4*>(hr + 4 * q);
    float tmp[4] = {v.x, v.y, v.z, v.w};
    #pragma unroll
    for (int u = 0; u < 4; ++u) {
      int j = 4 * q + u;
      float hv = fmaf(tmp[u], scsh[j], scsh[HID + j]);
      h[j] = hv > 0.f ? hv : 0.f;
    }
  }

  float acc[HID];
  // z1 = h @ W2l
  #pragma unroll
  for (int j = 0; j < HID; ++j) acc[j] = 0.f;
  #pragma unroll
  for (int k = 0; k < HID; ++k) {
    float hk = h[k];
    const float* wrow = W2l + (size_t)k * HID;
    #pragma unroll
    for (int j = 0; j < HID; ++j) acc[j] = fmaf(hk, wrow[j], acc[j]);
  }
  {
    float4* o = reinterpret_cast<float4*>(z1 + (size_t)n * HID);
    #pragma unroll
    for (int q = 0; q < HID / 4; ++q)
      o[q] = make_float4(acc[4*q], acc[4*q+1], acc[4*q+2], acc[4*q+3]);
  }
  // z2 = h @ W2r
  #pragma unroll
  for (int j = 0; j < HID; ++j) acc[j] = 0.f;
  #pragma unroll
  for (int k = 0; k < HID; ++k) {
    float hk = h[k];
    const float* wrow = W2r + (size_t)k * HID;
    #pragma unroll
    for (int j = 0; j < HID; ++j) acc[j] = fmaf(hk, wrow[j], acc[j]);
  }
  {
    float4* o = reinterpret_cast<float4*>(z2 + (size_t)n * HID);
    #pragma unroll
    for (int q = 0; q < HID / 4; ++q)
      o[q] = make_float4(acc[4*q], acc[4*q+1], acc[4*q+2], acc[4*q+3]);
  }
}

// ---------------------------------------------------------------------------
// pool: h2 = C/max(cnt,1) + b2 + z2; per-graph mean accumulation.
// batch is sorted -> register-accumulate per graph, flush on change.
// Threads with j==0 also count nodes per graph.
// Launch: grid*block multiple of 64.
// ---------------------------------------------------------------------------
__global__ __launch_bounds__(256) void pool_kernel(
    const float* __restrict__ C, const float* __restrict__ z2,
    const float* __restrict__ cnt, const float* __restrict__ b2,
    const int* __restrict__ batch, float* __restrict__ poolacc,
    float* __restrict__ poolcnt) {
  long long tid = (long long)blockIdx.x * blockDim.x + threadIdx.x;
  long long stride = (long long)gridDim.x * blockDim.x;  // multiple of 64
  int j = (int)(tid & 63);
  float bj = b2[j];
  bool docnt = (j == 0);

  int curb = -1;
  float accv = 0.f, cntv = 0.f;
  for (long long idx = tid; idx < (long long)N_NODES * HID; idx += stride) {
    int n = (int)(idx >> 6);
    float c = cnt[n];
    c = c > 1.f ? c : 1.f;
    float val = C[idx] / c + bj + z2[idx];
    int b = batch[n];
    if (b != curb) {
      if (curb >= 0) {
        unsafeAtomicAdd(&poolacc[curb * HID + j], accv);
        if (docnt) unsafeAtomicAdd(&poolcnt[curb], cntv);
      }
      curb = b;
      accv = 0.f;
      cntv = 0.f;
    }
    accv += val;
    cntv += 1.f;
  }
  if (curb >= 0) {
    unsafeAtomicAdd(&poolacc[curb * HID + j], accv);
    if (docnt) unsafeAtomicAdd(&poolcnt[curb], cntv);
  }
}

// ---------------------------------------------------------------------------
// final: out = poolacc / max(poolcnt, 1)
// ---------------------------------------------------------------------------
__global__ void final_kernel(const float* __restrict__ poolacc,
                             const float* __restrict__ poolcnt,
                             float* __restrict__ out) {
  int t = blockIdx.x * blockDim.x + threadIdx.x;
  if (t >= NGRAPH * HID) return;
  int b = t >> 6;
  float c = poolcnt[b];
  c = c > 1.f ? c : 1.f;
  out[t] = poolacc[t] / c;
}

// ---------------------------------------------------------------------------
extern "C" void kernel_launch(void* const* d_in, const int* in_sizes, int n_in,
                              void* d_out, int out_size, void* d_ws,
                              size_t ws_size, hipStream_t stream) {
  const float* x      = (const float*)d_in[0];
  const int*   ei     = (const int*)d_in[1];
  const int*   batch  = (const int*)d_in[2];
  const float* W1l    = (const float*)d_in[3];
  const float* b1     = (const float*)d_in[4];
  const float* W1r    = (const float*)d_in[5];
  const float* gamma1 = (const float*)d_in[6];
  const float* beta1  = (const float*)d_in[7];
  const float* W2l    = (const float*)d_in[8];
  const float* b2     = (const float*)d_in[9];
  const float* W2r    = (const float*)d_in[10];

  const int* src = ei;            // edge_index[0]
  const int* dst = ei + E_EDGES;  // edge_index[1]

  float* ws = (float*)d_ws;
  size_t off = 0;
  float* A  = ws + off; off += (size_t)N_NODES * HID;  // y1 -> z1
  float* Bb = ws + off; off += (size_t)N_NODES * HID;  // y2 -> z2
  float* Cc = ws + off; off += (size_t)N_NODES * HID;  // agg accum / h_raw
  float* cnt     = ws + off; off += N_NODES;
  float* stats   = ws + off; off += 2 * HID;
  float* scsh    = ws + off; off += 2 * HID;
  float* poolacc = ws + off; off += NGRAPH * HID;
  float* poolcnt = ws + off; off += NGRAPH;

  // zero Cc + cnt + stats + scsh + poolacc + poolcnt in one shot
  size_t zero_elems = (size_t)N_NODES * HID + N_NODES + 2 * HID + 2 * HID +
                      NGRAPH * HID + NGRAPH;
  hipMemsetAsync(Cc, 0, zero_elems * sizeof(float), stream);

  mm1_kernel<<<(N_NODES + 255) / 256, 256, 0, stream>>>(x, W1l, W1r, A, Bb);

  agg_kernel<true><<<(E_EDGES * 16 + 255) / 256, 256, 0, stream>>>(
      A, src, dst, Cc, cnt);

  hcalc_kernel<<<512, 256, 0, stream>>>(Cc, Bb, cnt, b1, stats);

  bnstats_kernel<<<1, 64, 0, stream>>>(stats, gamma1, beta1, scsh);

  mm2_kernel<<<(N_NODES + 255) / 256, 256, 0, stream>>>(Cc, scsh, W2l, W2r, A,
                                                        Bb);

  hipMemsetAsync(Cc, 0, (size_t)N_NODES * HID * sizeof(float), stream);

  agg_kernel<false><<<(E_EDGES * 16 + 255) / 256, 256, 0, stream>>>(
      A, src, dst, Cc, nullptr);

  pool_kernel<<<512, 256, 0, stream>>>(Cc, Bb, cnt, b2, batch, poolacc,
                                       poolcnt);

  final_kernel<<<2, 256, 0, stream>>>(poolacc, poolcnt, (float*)d_out);
}

// Round 2
// 659.070 us; speedup vs baseline: 4.9056x; 4.9056x over previous
//
#include <hip/hip_runtime.h>

#define N_NODES 100000
#define E_EDGES 1600000
#define DIM 128
#define HID 64
#define NGRAPH 8
#define EPSBN 1e-5f

#define SCAN_BLK 1024
#define NSCAN_BLKS ((N_NODES + SCAN_BLK - 1) / SCAN_BLK)  // 98

// ---------------------------------------------------------------------------
// hist: deg[d] += 1 for each edge (int atomics)
// ---------------------------------------------------------------------------
__global__ __launch_bounds__(256) void hist_kernel(const int* __restrict__ dst,
                                                   int* __restrict__ deg) {
  int e = blockIdx.x * blockDim.x + threadIdx.x;
  if (e >= E_EDGES) return;
  atomicAdd(&deg[dst[e]], 1);
}

// ---------------------------------------------------------------------------
// scanA: per-block inclusive scan of deg -> incl (= rowptr+1), block sums
// ---------------------------------------------------------------------------
__global__ __launch_bounds__(SCAN_BLK) void scanA_kernel(
    const int* __restrict__ deg, int* __restrict__ incl,
    int* __restrict__ bsum) {
  __shared__ int buf[SCAN_BLK];
  int gid = blockIdx.x * SCAN_BLK + threadIdx.x;
  int v = (gid < N_NODES) ? deg[gid] : 0;
  buf[threadIdx.x] = v;
  __syncthreads();
  for (int off = 1; off < SCAN_BLK; off <<= 1) {
    int t = buf[threadIdx.x];
    int add = (threadIdx.x >= off) ? buf[threadIdx.x - off] : 0;
    __syncthreads();
    buf[threadIdx.x] = t + add;
    __syncthreads();
  }
  if (gid < N_NODES) incl[gid] = buf[threadIdx.x];
  if (threadIdx.x == SCAN_BLK - 1) bsum[blockIdx.x] = buf[SCAN_BLK - 1];
}

// ---------------------------------------------------------------------------
// scanB: inclusive scan of the 98 block sums (single block, in place)
// ---------------------------------------------------------------------------
__global__ __launch_bounds__(128) void scanB_kernel(int* __restrict__ bsum) {
  __shared__ int buf[128];
  int tid = threadIdx.x;
  buf[tid] = (tid < NSCAN_BLKS) ? bsum[tid] : 0;
  __syncthreads();
  for (int off = 1; off < 128; off <<= 1) {
    int t = buf[tid];
    int add = (tid >= off) ? buf[tid - off] : 0;
    __syncthreads();
    buf[tid] = t + add;
    __syncthreads();
  }
  if (tid < NSCAN_BLKS) bsum[tid] = buf[tid];
}

// ---------------------------------------------------------------------------
// scanC: add block offsets -> rowptr[i+1] (in place over incl), cursor[i]
// ---------------------------------------------------------------------------
__global__ __launch_bounds__(256) void scanC_kernel(
    int* __restrict__ rowptr, const int* __restrict__ bsum,
    const int* __restrict__ deg, int* __restrict__ cursor) {
  int i = blockIdx.x * blockDim.x + threadIdx.x;
  if (i >= N_NODES) return;
  int blk = i >> 10;
  int off = (blk > 0) ? bsum[blk - 1] : 0;
  int v = rowptr[i + 1] + off;  // inclusive prefix through i
  rowptr[i + 1] = v;
  cursor[i] = v - deg[i];
  if (i == 0) rowptr[0] = 0;
}

// ---------------------------------------------------------------------------
// fill: counting-sort edges into CSR by dst
// ---------------------------------------------------------------------------
__global__ __launch_bounds__(256) void fill_kernel(const int* __restrict__ src,
                                                   const int* __restrict__ dst,
                                                   int* __restrict__ cursor,
                                                   int* __restrict__ csr) {
  int e = blockIdx.x * blockDim.x + threadIdx.x;
  if (e >= E_EDGES) return;
  int pos = atomicAdd(&cursor[dst[e]], 1);
  csr[pos] = src[e];
}

// ---------------------------------------------------------------------------
// gather: one wave per node; mean of y[src] rows over the node's CSR range.
// Each lane owns one of the 64 columns; per edge one coalesced 256B load.
// Writes mean directly (÷ max(deg,1)).
// ---------------------------------------------------------------------------
__global__ __launch_bounds__(256) void gather_kernel(
    const float* __restrict__ y, const int* __restrict__ csr,
    const int* __restrict__ rowptr, float* __restrict__ outC) {
  int wid = (blockIdx.x * blockDim.x + threadIdx.x) >> 6;
  int lane = threadIdx.x & 63;
  if (wid >= N_NODES) return;
  int start = rowptr[wid];
  int end = rowptr[wid + 1];
  float acc = 0.f;
  for (int base = start; base < end; base += 64) {
    int e = base + lane;
    int s = (e < end) ? csr[e] : 0;
    int m = end - base;
    m = m < 64 ? m : 64;
    for (int i = 0; i < m; ++i) {
      int si = __shfl(s, i);
      acc += y[(size_t)si * HID + lane];
    }
  }
  int deg = end - start;
  float inv = 1.f / (float)(deg > 1 ? deg : 1);
  outC[(size_t)wid * HID + lane] = acc * inv;
}

// ---------------------------------------------------------------------------
// mm1: y1 = x @ W1l, y2 = x @ W1r (thread per row; uniform W -> s_loads)
// ---------------------------------------------------------------------------
__global__ __launch_bounds__(256) void mm1_kernel(
    const float* __restrict__ x, const float* __restrict__ W1l,
    const float* __restrict__ W1r, float* __restrict__ y1,
    float* __restrict__ y2) {
  int n = blockIdx.x * blockDim.x + threadIdx.x;
  if (n >= N_NODES) return;
  const float* xr = x + (size_t)n * DIM;

  float acc[HID];
  #pragma unroll
  for (int j = 0; j < HID; ++j) acc[j] = 0.f;
  for (int k = 0; k < DIM; k += 4) {
    float4 xv = *reinterpret_cast<const float4*>(xr + k);
    float xs[4] = {xv.x, xv.y, xv.z, xv.w};
    #pragma unroll
    for (int kk = 0; kk < 4; ++kk) {
      const float* wrow = W1l + (size_t)(k + kk) * HID;
      float xk = xs[kk];
      #pragma unroll
      for (int j = 0; j < HID; ++j) acc[j] = fmaf(xk, wrow[j], acc[j]);
    }
  }
  {
    float4* o = reinterpret_cast<float4*>(y1 + (size_t)n * HID);
    #pragma unroll
    for (int q = 0; q < HID / 4; ++q)
      o[q] = make_float4(acc[4*q], acc[4*q+1], acc[4*q+2], acc[4*q+3]);
  }
  #pragma unroll
  for (int j = 0; j < HID; ++j) acc[j] = 0.f;
  for (int k = 0; k < DIM; k += 4) {
    float4 xv = *reinterpret_cast<const float4*>(xr + k);
    float xs[4] = {xv.x, xv.y, xv.z, xv.w};
    #pragma unroll
    for (int kk = 0; kk < 4; ++kk) {
      const float* wrow = W1r + (size_t)(k + kk) * HID;
      float xk = xs[kk];
      #pragma unroll
      for (int j = 0; j < HID; ++j) acc[j] = fmaf(xk, wrow[j], acc[j]);
    }
  }
  {
    float4* o = reinterpret_cast<float4*>(y2 + (size_t)n * HID);
    #pragma unroll
    for (int q = 0; q < HID / 4; ++q)
      o[q] = make_float4(acc[4*q], acc[4*q+1], acc[4*q+2], acc[4*q+3]);
  }
}

// ---------------------------------------------------------------------------
// hcalc: h_raw = C + b1 + y2 (C already holds the mean), in place into C.
// Fused BN statistics -> stats[0..63]=sum, stats[64..127]=sumsq.
// ---------------------------------------------------------------------------
__global__ __launch_bounds__(256) void hcalc_kernel(
    float* __restrict__ C, const float* __restrict__ y2,
    const float* __restrict__ b1, float* __restrict__ stats) {
  __shared__ float ssum[HID];
  __shared__ float ssq[HID];
  int tid = threadIdx.x;
  if (tid < HID) { ssum[tid] = 0.f; ssq[tid] = 0.f; }
  __syncthreads();

  int j = tid & 63;
  float bj = b1[j];
  float lsum = 0.f, lsq = 0.f;
  long long stride = (long long)gridDim.x * blockDim.x;  // multiple of 64
  for (long long idx = (long long)blockIdx.x * blockDim.x + tid;
       idx < (long long)N_NODES * HID; idx += stride) {
    float val = C[idx] + bj + y2[idx];
    C[idx] = val;
    lsum += val;
    lsq = fmaf(val, val, lsq);
  }
  atomicAdd(&ssum[j], lsum);
  atomicAdd(&ssq[j], lsq);
  __syncthreads();
  if (tid < HID) {
    unsafeAtomicAdd(&stats[tid], ssum[tid]);
    unsafeAtomicAdd(&stats[HID + tid], ssq[tid]);
  }
}

// ---------------------------------------------------------------------------
__global__ void bnstats_kernel(const float* __restrict__ stats,
                               const float* __restrict__ gamma,
                               const float* __restrict__ beta,
                               float* __restrict__ scsh) {
  int j = threadIdx.x;  // 64 threads
  float inv_n = 1.0f / (float)N_NODES;
  float mu = stats[j] * inv_n;
  float var = stats[HID + j] * inv_n - mu * mu;
  float sc = gamma[j] * rsqrtf(var + EPSBN);
  scsh[j] = sc;
  scsh[HID + j] = beta[j] - mu * sc;
}

// ---------------------------------------------------------------------------
// mm2: h = relu(h_raw*scale+shift); z1 = h@W2l; z2 = h@W2r (thread per row)
// ---------------------------------------------------------------------------
__global__ __launch_bounds__(256) void mm2_kernel(
    const float* __restrict__ C, const float* __restrict__ scsh,
    const float* __restrict__ W2l, const float* __restrict__ W2r,
    float* __restrict__ z1, float* __restrict__ z2) {
  int n = blockIdx.x * blockDim.x + threadIdx.x;
  if (n >= N_NODES) return;
  const float* hr = C + (size_t)n * HID;

  float h[HID];
  #pragma unroll
  for (int q = 0; q < HID / 4; ++q) {
    float4 v = *reinterpret_cast<const float4*>(hr + 4 * q);
    float tmp[4] = {v.x, v.y, v.z, v.w};
    #pragma unroll
    for (int u = 0; u < 4; ++u) {
      int j = 4 * q + u;
      float hv = fmaf(tmp[u], scsh[j], scsh[HID + j]);
      h[j] = hv > 0.f ? hv : 0.f;
    }
  }

  float acc[HID];
  #pragma unroll
  for (int j = 0; j < HID; ++j) acc[j] = 0.f;
  #pragma unroll
  for (int k = 0; k < HID; ++k) {
    float hk = h[k];
    const float* wrow = W2l + (size_t)k * HID;
    #pragma unroll
    for (int j = 0; j < HID; ++j) acc[j] = fmaf(hk, wrow[j], acc[j]);
  }
  {
    float4* o = reinterpret_cast<float4*>(z1 + (size_t)n * HID);
    #pragma unroll
    for (int q = 0; q < HID / 4; ++q)
      o[q] = make_float4(acc[4*q], acc[4*q+1], acc[4*q+2], acc[4*q+3]);
  }
  #pragma unroll
  for (int j = 0; j < HID; ++j) acc[j] = 0.f;
  #pragma unroll
  for (int k = 0; k < HID; ++k) {
    float hk = h[k];
    const float* wrow = W2r + (size_t)k * HID;
    #pragma unroll
    for (int j = 0; j < HID; ++j) acc[j] = fmaf(hk, wrow[j], acc[j]);
  }
  {
    float4* o = reinterpret_cast<float4*>(z2 + (size_t)n * HID);
    #pragma unroll
    for (int q = 0; q < HID / 4; ++q)
      o[q] = make_float4(acc[4*q], acc[4*q+1], acc[4*q+2], acc[4*q+3]);
  }
}

// ---------------------------------------------------------------------------
// pool: h2 = C + b2 + z2 (C holds mean); per-graph mean accumulation.
// batch sorted -> contiguous node ranges per wave, flush on graph change.
// ---------------------------------------------------------------------------
#define POOL_WAVES 2048
__global__ __launch_bounds__(256) void pool_kernel(
    const float* __restrict__ C, const float* __restrict__ z2,
    const float* __restrict__ b2, const int* __restrict__ batch,
    float* __restrict__ poolacc, float* __restrict__ poolcnt) {
  int wave = (blockIdx.x * blockDim.x + threadIdx.x) >> 6;
  int j = threadIdx.x & 63;
  const int chunk = (N_NODES + POOL_WAVES - 1) / POOL_WAVES;
  int n0 = wave * chunk;
  int n1 = n0 + chunk;
  n1 = n1 < N_NODES ? n1 : N_NODES;
  if (n0 >= n1) return;
  float bj = b2[j];
  bool docnt = (j == 0);

  int curb = -1;
  float accv = 0.f, cntv = 0.f;
  for (int n = n0; n < n1; ++n) {
    float val = C[(size_t)n * HID + j] + bj + z2[(size_t)n * HID + j];
    int b = batch[n];
    if (b != curb) {
      if (curb >= 0) {
        unsafeAtomicAdd(&poolacc[curb * HID + j], accv);
        if (docnt) unsafeAtomicAdd(&poolcnt[curb], cntv);
      }
      curb = b;
      accv = 0.f;
      cntv = 0.f;
    }
    accv += val;
    cntv += 1.f;
  }
  if (curb >= 0) {
    unsafeAtomicAdd(&poolacc[curb * HID + j], accv);
    if (docnt) unsafeAtomicAdd(&poolcnt[curb], cntv);
  }
}

// ---------------------------------------------------------------------------
__global__ void final_kernel(const float* __restrict__ poolacc,
                             const float* __restrict__ poolcnt,
                             float* __restrict__ out) {
  int t = blockIdx.x * blockDim.x + threadIdx.x;
  if (t >= NGRAPH * HID) return;
  int b = t >> 6;
  float c = poolcnt[b];
  c = c > 1.f ? c : 1.f;
  out[t] = poolacc[t] / c;
}

// ---------------------------------------------------------------------------
extern "C" void kernel_launch(void* const* d_in, const int* in_sizes, int n_in,
                              void* d_out, int out_size, void* d_ws,
                              size_t ws_size, hipStream_t stream) {
  const float* x      = (const float*)d_in[0];
  const int*   ei     = (const int*)d_in[1];
  const int*   batch  = (const int*)d_in[2];
  const float* W1l    = (const float*)d_in[3];
  const float* b1     = (const float*)d_in[4];
  const float* W1r    = (const float*)d_in[5];
  const float* gamma1 = (const float*)d_in[6];
  const float* beta1  = (const float*)d_in[7];
  const float* W2l    = (const float*)d_in[8];
  const float* b2     = (const float*)d_in[9];
  const float* W2r    = (const float*)d_in[10];

  const int* src = ei;            // edge_index[0]
  const int* dst = ei + E_EDGES;  // edge_index[1]

  float* ws = (float*)d_ws;
  size_t off = 0;
  float* A  = ws + off; off += (size_t)N_NODES * HID;  // y1 -> z1
  float* Bb = ws + off; off += (size_t)N_NODES * HID;  // y2 -> z2
  float* Cc = ws + off; off += (size_t)N_NODES * HID;  // agg mean / h_raw
  // zero-region start
  int* deg      = (int*)(ws + off); off += N_NODES;
  float* stats  = ws + off; off += 2 * HID;
  float* poolacc= ws + off; off += NGRAPH * HID;
  float* poolcnt= ws + off; off += NGRAPH;
  size_t zero_elems = N_NODES + 2 * HID + NGRAPH * HID + NGRAPH;
  // zero-region end
  float* scsh   = ws + off; off += 2 * HID;
  int* rowptr   = (int*)(ws + off); off += N_NODES + 1;
  int* cursor   = (int*)(ws + off); off += N_NODES;
  int* bsum     = (int*)(ws + off); off += 128;
  int* csr      = (int*)(ws + off); off += E_EDGES;

  hipMemsetAsync(deg, 0, zero_elems * sizeof(float), stream);

  // ---- CSR build (shared by both layers) ----
  hist_kernel<<<(E_EDGES + 255) / 256, 256, 0, stream>>>(dst, deg);
  scanA_kernel<<<NSCAN_BLKS, SCAN_BLK, 0, stream>>>(deg, rowptr + 1, bsum);
  scanB_kernel<<<1, 128, 0, stream>>>(bsum);
  scanC_kernel<<<(N_NODES + 255) / 256, 256, 0, stream>>>(rowptr, bsum, deg,
                                                          cursor);
  fill_kernel<<<(E_EDGES + 255) / 256, 256, 0, stream>>>(src, dst, cursor,
                                                         csr);

  // ---- layer 1 ----
  mm1_kernel<<<(N_NODES + 255) / 256, 256, 0, stream>>>(x, W1l, W1r, A, Bb);
  gather_kernel<<<(N_NODES * 64 + 255) / 256, 256, 0, stream>>>(A, csr,
                                                                rowptr, Cc);
  hcalc_kernel<<<512, 256, 0, stream>>>(Cc, Bb, b1, stats);
  bnstats_kernel<<<1, 64, 0, stream>>>(stats, gamma1, beta1, scsh);

  // ---- layer 2 ----
  mm2_kernel<<<(N_NODES + 255) / 256, 256, 0, stream>>>(Cc, scsh, W2l, W2r, A,
                                                        Bb);
  gather_kernel<<<(N_NODES * 64 + 255) / 256, 256, 0, stream>>>(A, csr,
                                                                rowptr, Cc);
  pool_kernel<<<(POOL_WAVES * 64 + 255) / 256, 256, 0, stream>>>(
      Cc, Bb, b2, batch, poolacc, poolcnt);
  final_kernel<<<2, 256, 0, stream>>>(poolacc, poolcnt, (float*)d_out);
}